// Round 3
// baseline (178.517 us; speedup 1.0000x reference)
//
#include <hip/hip_runtime.h>

// ETNN layer, N=50000 cells, HID=64, DEG=16 neighbors, 4 nodes/cell, sp=3.
// prep: centroids + fp32->bf16 features + positions passthrough + weight
//       pre-swizzle (bf16 MFMA fragment layout) into ws
// msg : per-cell [16 nbr x 128] @ W1 (+geom rank-1), silu, @ W2, mean -> msg
// upd : per-16-cell tile [feat|msg] @ Wu1, silu, @ Wu2, residual
//
// MFMA layouts (HW-verified, m89/m91/m120):
//   A[m=lane&15][k=quad*8+j], B[k=quad*8+j][n=lane&15],
//   D[row=quad*4+reg][col=lane&15].
// Layer 1 computed transposed (D1 = W^T x X^T), weight frags in registers
// (vector-loaded from pre-swizzled bf16); X B-frags straight from global.
// Hidden round-trips through wave-private LDS; ordering via in-order DS pipe
// + __threadfence_block + may_alias types (no block barrier — waves free-run).

#define DEG 16

typedef __attribute__((ext_vector_type(8))) short short8;   // 8 bf16
typedef __attribute__((ext_vector_type(4))) float f32x4;    // MFMA acc
typedef uint2 uint2_a __attribute__((may_alias));
typedef uint4 uint4_a __attribute__((may_alias));

union HbRd { uint4_a u; short8 s; };

__device__ __forceinline__ unsigned f2bf(float f) {
  unsigned u = __float_as_uint(f);
  return (u + 0x7FFFu + ((u >> 16) & 1u)) >> 16;   // RNE fp32->bf16
}

__device__ __forceinline__ float silu(float h) {
  return h / (1.f + __expf(-h));
}

// ---------------------------------------------------------------- prep ----
// t in [0, 800000): features fp32 -> bf16 (4 elems/thread)
// t in [800000, 950000): positions copy to out tail (float4/thread)
// t in [950000, 1000000): centroid of 4 nodes -> cent4
// t in [1000000, 1024576): weight pre-swizzle into bf16 fragment layout
__global__ __launch_bounds__(256) void prep_kernel(
    const float* __restrict__ feat, const float* __restrict__ pos,
    const float* __restrict__ W1, const float* __restrict__ W2,
    const float* __restrict__ Wu1, const float* __restrict__ Wu2,
    unsigned short* __restrict__ featb, float* __restrict__ cent4,
    float* __restrict__ outpos,
    unsigned short* __restrict__ w1b, unsigned short* __restrict__ w2b,
    unsigned short* __restrict__ wu1b, unsigned short* __restrict__ wu2b)
{
  int t = blockIdx.x * 256 + threadIdx.x;
  if (t < 800000) {
    const float4 v = ((const float4*)feat)[t];
    ushort4 b;
    b.x = (unsigned short)f2bf(v.x);
    b.y = (unsigned short)f2bf(v.y);
    b.z = (unsigned short)f2bf(v.z);
    b.w = (unsigned short)f2bf(v.w);
    ((ushort4*)featb)[t] = b;
  } else if (t < 950000) {
    const int p = t - 800000;
    ((float4*)outpos)[p] = ((const float4*)pos)[p];
  } else if (t < 1000000) {
    const int i = t - 950000;
    const float4* pp = (const float4*)(pos + 12 * i);   // 48B-aligned
    const float4 a = pp[0], b = pp[1], c = pp[2];
    float4 o;
    o.x = (a.x + a.w + b.z + c.y) * 0.25f;
    o.y = (a.y + b.x + b.w + c.z) * 0.25f;
    o.z = (a.z + b.y + c.x + c.w) * 0.25f;
    o.w = 0.f;
    ((float4*)cent4)[i] = o;
  } else if (t < 1024576) {
    const int r = t - 1000000;
    // elem index = [mt|nt]*.. + kk*.. + quad*128 + l15*8 + j  (see msg loads)
    if (r < 8192) {          // w1b: A-frags of W1^T (4 mt x 4 kk)
      const int j = r & 7, l = (r >> 3) & 15, q = (r >> 7) & 3;
      const int kk = (r >> 9) & 3, mt = r >> 11;
      const int k = kk * 32 + q * 8 + j;
      w1b[r] = (unsigned short)f2bf(W1[k * 64 + mt * 16 + l]);
    } else if (r < 12288) {  // w2b: B-frags of W2 (4 nt x 2 kk)
      const int s = r - 8192;
      const int j = s & 7, l = (s >> 3) & 15, q = (s >> 7) & 3;
      const int kk = (s >> 9) & 1, nt = s >> 10;
      const int k = kk * 32 + q * 8 + j;
      w2b[s] = (unsigned short)f2bf(W2[k * 64 + nt * 16 + l]);
    } else if (r < 20480) {  // wu1b: A-frags of Wu1^T
      const int s = r - 12288;
      const int j = s & 7, l = (s >> 3) & 15, q = (s >> 7) & 3;
      const int kk = (s >> 9) & 3, mt = s >> 11;
      const int k = kk * 32 + q * 8 + j;
      wu1b[s] = (unsigned short)f2bf(Wu1[k * 64 + mt * 16 + l]);
    } else {                 // wu2b: B-frags of Wu2
      const int s = r - 20480;
      const int j = s & 7, l = (s >> 3) & 15, q = (s >> 7) & 3;
      const int kk = (s >> 9) & 1, nt = s >> 10;
      const int k = kk * 32 + q * 8 + j;
      wu2b[s] = (unsigned short)f2bf(Wu2[k * 64 + nt * 16 + l]);
    }
  }
}

// ----------------------------------------------------------------- msg ----
__global__ __launch_bounds__(256) void msg_kernel(
    const unsigned short* __restrict__ featb,
    const float4* __restrict__ cent4,
    const int* __restrict__ nbr,
    const unsigned short* __restrict__ w1b,
    const unsigned short* __restrict__ w2b,
    const float* __restrict__ b1, const float* __restrict__ W1,
    const float* __restrict__ b2,
    unsigned short* __restrict__ msgb)
{
  __shared__ uint4 HbAll[4 * 144];   // per wave: 16 rows x 144 B
  const int lane = threadIdx.x & 63;
  const int wid  = threadIdx.x >> 6;
  const int quad = lane >> 4;
  const int l15  = lane & 15;
  char* Hb = (char*)(HbAll + wid * 144);

  // weight fragments: pure 16B vector loads from pre-swizzled bf16
  short8 w1f[4][4];
  #pragma unroll
  for (int mt = 0; mt < 4; ++mt)
    #pragma unroll
    for (int kk = 0; kk < 4; ++kk)
      w1f[mt][kk] = *(const short8*)(w1b + (((mt * 4 + kk) * 4 + quad) << 7) + l15 * 8);
  short8 w2f[4][2];
  #pragma unroll
  for (int nt = 0; nt < 4; ++nt)
    #pragma unroll
    for (int kk = 0; kk < 2; ++kk)
      w2f[nt][kk] = *(const short8*)(w2b + (((nt * 2 + kk) * 4 + quad) << 7) + l15 * 8);
  f32x4 b1f[4], w1lf[4];
  #pragma unroll
  for (int mt = 0; mt < 4; ++mt) {
    b1f[mt]  = *(const f32x4*)(b1 + mt * 16 + quad * 4);
    w1lf[mt] = *(const f32x4*)(W1 + 8192 + mt * 16 + quad * 4); // geom row 128
  }
  float b2v[4];
  #pragma unroll
  for (int nt = 0; nt < 4; ++nt) b2v[nt] = b2[nt * 16 + l15];

  // 3125 blocks x 4 waves x 4 cells
  for (int c0 = blockIdx.x * 4; c0 < 50000; c0 += gridDim.x * 4) {
    const int cell = c0 + wid;

    int nj = 0; float g = 0.f;
    if (lane < 16) {
      nj = nbr[cell * DEG + lane];
      const float4 ci = cent4[cell];
      const float4 cj = cent4[nj];
      const float dx = ci.x - cj.x, dy = ci.y - cj.y, dz = ci.z - cj.z;
      g = sqrtf(dx * dx + dy * dy + dz * dz);
    }
    const float g_r  = __shfl(g, l15);   // geom of row r = lane&15
    const int   nj_r = __shfl(nj, l15);  // neighbor id of row r

    // layer 1: hidden^T = W1^T x X^T; B-frags straight from global
    f32x4 acc[4] = {};
    #pragma unroll
    for (int kk = 0; kk < 4; ++kk) {
      const unsigned short* src = (kk < 2)
          ? featb + cell * 64 + kk * 32 + quad * 8
          : featb + nj_r * 64 + (kk - 2) * 32 + quad * 8;
      const short8 bf = *(const short8*)src;
      #pragma unroll
      for (int mt = 0; mt < 4; ++mt)
        acc[mt] = __builtin_amdgcn_mfma_f32_16x16x32_bf16(w1f[mt][kk], bf, acc[mt], 0, 0, 0);
    }

    // epilogue: +b1 +geom*W1[128], silu, pack 4 consecutive cols
    #pragma unroll
    for (int mt = 0; mt < 4; ++mt) {
      float sv[4];
      #pragma unroll
      for (int rg = 0; rg < 4; ++rg) {
        const float h = acc[mt][rg] + b1f[mt][rg] + g_r * w1lf[mt][rg];
        sv[rg] = silu(h);
      }
      uint2 pk;
      pk.x = f2bf(sv[0]) | (f2bf(sv[1]) << 16);
      pk.y = f2bf(sv[2]) | (f2bf(sv[3]) << 16);
      *(uint2_a*)(Hb + l15 * 144 + mt * 32 + quad * 8) = pk;
    }

    __threadfence_block();   // LDS writes visible before reads (wave-private)

    // layer 2: h2 = hid x W2
    f32x4 acc2[4] = {};
    #pragma unroll
    for (int kk = 0; kk < 2; ++kk) {
      HbRd t; t.u = *(const uint4_a*)(Hb + l15 * 144 + kk * 64 + quad * 16);
      const short8 af = t.s;
      #pragma unroll
      for (int nt = 0; nt < 4; ++nt)
        acc2[nt] = __builtin_amdgcn_mfma_f32_16x16x32_bf16(af, w2f[nt][kk], acc2[nt], 0, 0, 0);
    }

    // mean over 16 neighbors: 4 rows in-lane + cross-quad shfl_xor
    #pragma unroll
    for (int nt = 0; nt < 4; ++nt) {
      float s = acc2[nt][0] + acc2[nt][1] + acc2[nt][2] + acc2[nt][3];
      s += __shfl_xor(s, 16);
      s += __shfl_xor(s, 32);
      const float m = s * 0.0625f + b2v[nt];
      if (lane < 16)
        msgb[cell * 64 + nt * 16 + lane] = (unsigned short)f2bf(m);
    }
  }
}

// ----------------------------------------------------------------- upd ----
__global__ __launch_bounds__(256) void upd_kernel(
    const unsigned short* __restrict__ featb,
    const unsigned short* __restrict__ msgb,
    const float* __restrict__ feat,
    const unsigned short* __restrict__ wu1b,
    const unsigned short* __restrict__ wu2b,
    const float* __restrict__ bu1, const float* __restrict__ bu2,
    float* __restrict__ outf)
{
  __shared__ uint4 HbAll[4 * 144];
  const int lane = threadIdx.x & 63;
  const int wid  = threadIdx.x >> 6;
  const int quad = lane >> 4;
  const int l15  = lane & 15;
  char* Hb = (char*)(HbAll + wid * 144);

  short8 wu1f[4][4];
  #pragma unroll
  for (int mt = 0; mt < 4; ++mt)
    #pragma unroll
    for (int kk = 0; kk < 4; ++kk)
      wu1f[mt][kk] = *(const short8*)(wu1b + (((mt * 4 + kk) * 4 + quad) << 7) + l15 * 8);
  short8 wu2f[4][2];
  #pragma unroll
  for (int nt = 0; nt < 4; ++nt)
    #pragma unroll
    for (int kk = 0; kk < 2; ++kk)
      wu2f[nt][kk] = *(const short8*)(wu2b + (((nt * 2 + kk) * 4 + quad) << 7) + l15 * 8);
  f32x4 bu1f[4];
  #pragma unroll
  for (int mt = 0; mt < 4; ++mt)
    bu1f[mt] = *(const f32x4*)(bu1 + mt * 16 + quad * 4);
  float bu2v[4];
  #pragma unroll
  for (int nt = 0; nt < 4; ++nt) bu2v[nt] = bu2[nt * 16 + l15];

  // 3125 tiles of 16 cells; 781 blocks x 4 waves, tail masked
  for (int t0 = blockIdx.x * 4; t0 < 3125; t0 += gridDim.x * 4) {
    const int tile = t0 + wid;
    const bool act = (tile < 3125);
    const int  tt  = act ? tile : 3124;
    const int  cr  = tt * 16 + l15;

    f32x4 acc[4] = {};
    #pragma unroll
    for (int kk = 0; kk < 4; ++kk) {
      const unsigned short* src = (kk < 2)
          ? featb + cr * 64 + kk * 32 + quad * 8
          : msgb  + cr * 64 + (kk - 2) * 32 + quad * 8;
      const short8 bf = *(const short8*)src;
      #pragma unroll
      for (int mt = 0; mt < 4; ++mt)
        acc[mt] = __builtin_amdgcn_mfma_f32_16x16x32_bf16(wu1f[mt][kk], bf, acc[mt], 0, 0, 0);
    }

    #pragma unroll
    for (int mt = 0; mt < 4; ++mt) {
      float sv[4];
      #pragma unroll
      for (int rg = 0; rg < 4; ++rg)
        sv[rg] = silu(acc[mt][rg] + bu1f[mt][rg]);
      uint2 pk;
      pk.x = f2bf(sv[0]) | (f2bf(sv[1]) << 16);
      pk.y = f2bf(sv[2]) | (f2bf(sv[3]) << 16);
      *(uint2_a*)(Hb + l15 * 144 + mt * 32 + quad * 8) = pk;
    }

    __threadfence_block();

    f32x4 acc2[4] = {};
    #pragma unroll
    for (int kk = 0; kk < 2; ++kk) {
      HbRd t; t.u = *(const uint4_a*)(Hb + l15 * 144 + kk * 64 + quad * 16);
      const short8 af = t.s;
      #pragma unroll
      for (int nt = 0; nt < 4; ++nt)
        acc2[nt] = __builtin_amdgcn_mfma_f32_16x16x32_bf16(af, wu2f[nt][kk], acc2[nt], 0, 0, 0);
    }

    if (act) {
      #pragma unroll
      for (int nt = 0; nt < 4; ++nt)
        #pragma unroll
        for (int rg = 0; rg < 4; ++rg) {
          const int row = tt * 16 + quad * 4 + rg;
          const int col = nt * 16 + l15;
          outf[row * 64 + col] = feat[row * 64 + col] + acc2[nt][rg] + bu2v[nt];
        }
    }
  }
}

// -------------------------------------------------------------- launch ----
extern "C" void kernel_launch(void* const* d_in, const int* in_sizes, int n_in,
                              void* d_out, int out_size, void* d_ws, size_t ws_size,
                              hipStream_t stream)
{
  const float* feat = (const float*)d_in[0];
  const float* pos  = (const float*)d_in[1];
  const int*   nbr  = (const int*)d_in[2];
  const float* W1   = (const float*)d_in[3];
  const float* b1   = (const float*)d_in[4];
  const float* W2   = (const float*)d_in[5];
  const float* b2   = (const float*)d_in[6];
  const float* Wu1  = (const float*)d_in[7];
  const float* bu1  = (const float*)d_in[8];
  const float* Wu2  = (const float*)d_in[9];
  const float* bu2  = (const float*)d_in[10];
  float* out = (float*)d_out;

  // ws: featb bf16 @0 (6.4MB), msgb bf16 @6.4MB (6.4MB), cent4 @12.8MB
  // (0.8MB), then pre-swizzled bf16 weights (48KB total).
  unsigned short* featb = (unsigned short*)d_ws;
  unsigned short* msgb  = (unsigned short*)((char*)d_ws + 6400000);
  float*          cent4 = (float*)((char*)d_ws + 12800000);
  unsigned short* w1b   = (unsigned short*)((char*)d_ws + 13600000);
  unsigned short* w2b   = (unsigned short*)((char*)d_ws + 13616384);
  unsigned short* wu1b  = (unsigned short*)((char*)d_ws + 13624576);
  unsigned short* wu2b  = (unsigned short*)((char*)d_ws + 13640960);

  prep_kernel<<<4003, 256, 0, stream>>>(feat, pos, W1, W2, Wu1, Wu2,
                                        featb, cent4, out + 3200000,
                                        w1b, w2b, wu1b, wu2b);
  msg_kernel<<<3125, 256, 0, stream>>>(featb, (const float4*)cent4, nbr,
                                       w1b, w2b, b1, W1, b2, msgb);
  upd_kernel<<<781, 256, 0, stream>>>(featb, msgb, feat, wu1b, wu2b,
                                      bu1, bu2, out);
}

// Round 4
// 144.119 us; speedup vs baseline: 1.2387x; 1.2387x over previous
//
#include <hip/hip_runtime.h>

// ETNN layer, N=50000 cells, HID=64, DEG=16 neighbors, 4 nodes/cell, sp=3.
//
// Algorithmic split of the per-pair message MLP (bilinear concat-GEMM):
//   x@W1 = f_i@W1[0:64] + f_j@W1[64:128] + geom*W1[128]
// -> prep  : bf16 features, centroids, positions, weight frag pre-swizzle
// -> pq    : PQ[i] = feat[i] @ [W1_top | W1_bot]   (50000 x 64 x 128 GEMM)
// -> gather: s[i] = mean_d silu(P[i] + Q[nbr[i,d]] + g*w1L + b1)  (VALU+L2)
// -> tail  : msg = s@W2+b2; hu = silu([feat|msg]@Wu1+bu1); out = feat + hu@Wu2+bu2
//
// MFMA layouts (HW-verified): A[m=lane&15][k=quad*8+j], B[k=quad*8+j][n=lane&15],
// D[row=quad*4+reg][col=lane&15]. "Transposed" stages put weights in A so the
// D columns land 4-consecutive per lane (packed uint2 LDS/global writes).
// Wave-private LDS round-trips ordered by __threadfence_block + may_alias.

#define DEG 16

typedef __attribute__((ext_vector_type(8))) short short8;   // 8 bf16
typedef __attribute__((ext_vector_type(4))) float f32x4;    // MFMA acc
typedef uint2 uint2_a __attribute__((may_alias));
typedef uint4 uint4_a __attribute__((may_alias));

union HbRd { uint4_a u; short8 s; };

__device__ __forceinline__ unsigned f2bf(float f) {
  unsigned u = __float_as_uint(f);
  return (u + 0x7FFFu + ((u >> 16) & 1u)) >> 16;   // RNE fp32->bf16
}
__device__ __forceinline__ float bf2f(unsigned bits16) {
  return __uint_as_float(bits16 << 16);
}
__device__ __forceinline__ float silu(float h) {
  return h / (1.f + __expf(-h));
}

// ---------------------------------------------------------------- prep ----
// t<800000: feat fp32->bf16 x4 | <950000: positions copy | <1000000: centroid
// then 24576 threads of weight pre-swizzle into MFMA fragment order.
__global__ __launch_bounds__(256) void prep_kernel(
    const float* __restrict__ feat, const float* __restrict__ pos,
    const float* __restrict__ W1, const float* __restrict__ W2,
    const float* __restrict__ Wu1, const float* __restrict__ Wu2,
    unsigned short* __restrict__ featb, float* __restrict__ cent4,
    float* __restrict__ outpos,
    unsigned short* __restrict__ w1pq, unsigned short* __restrict__ w2t,
    unsigned short* __restrict__ wu1t, unsigned short* __restrict__ wu2b)
{
  int t = blockIdx.x * 256 + threadIdx.x;
  if (t < 800000) {
    const float4 v = ((const float4*)feat)[t];
    ushort4 b;
    b.x = (unsigned short)f2bf(v.x);
    b.y = (unsigned short)f2bf(v.y);
    b.z = (unsigned short)f2bf(v.z);
    b.w = (unsigned short)f2bf(v.w);
    ((ushort4*)featb)[t] = b;
  } else if (t < 950000) {
    const int p = t - 800000;
    ((float4*)outpos)[p] = ((const float4*)pos)[p];
  } else if (t < 1000000) {
    const int i = t - 950000;
    const float4* pp = (const float4*)(pos + 12 * i);
    const float4 a = pp[0], b = pp[1], c = pp[2];
    float4 o;
    o.x = (a.x + a.w + b.z + c.y) * 0.25f;
    o.y = (a.y + b.x + b.w + c.z) * 0.25f;
    o.z = (a.z + b.y + c.x + c.w) * 0.25f;
    o.w = 0.f;
    ((float4*)cent4)[i] = o;
  } else if (t < 1024576) {
    const int r = t - 1000000;
    if (r < 8192) {
      // w1pq: A-frags of [W1top|W1bot]^T, [mt 0..7][kk 0..1]
      const int j = r & 7, l = (r >> 3) & 15, q = (r >> 7) & 3;
      const int f = r >> 9, kk = f & 1, mt = f >> 1;
      const int k = kk * 32 + q * 8 + j;        // feat dim 0..63
      const int m = mt * 16 + l;                // pq col 0..127
      w1pq[r] = (unsigned short)f2bf(
          (m < 64) ? W1[k * 64 + m] : W1[(k + 64) * 64 + (m - 64)]);
    } else if (r < 12288) {
      // w2t: A-frags of W2^T, [mt 0..3][kk 0..1]
      const int s = r - 8192;
      const int j = s & 7, l = (s >> 3) & 15, q = (s >> 7) & 3;
      const int f = s >> 9, kk = f & 1, mt = f >> 1;
      const int k = kk * 32 + q * 8 + j;
      w2t[s] = (unsigned short)f2bf(W2[k * 64 + mt * 16 + l]);
    } else if (r < 20480) {
      // wu1t: A-frags of Wu1^T, [mt 0..3][kk 0..3]
      const int s = r - 12288;
      const int j = s & 7, l = (s >> 3) & 15, q = (s >> 7) & 3;
      const int f = s >> 9, kk = f & 3, mt = f >> 2;
      const int k = kk * 32 + q * 8 + j;        // 0..127
      wu1t[s] = (unsigned short)f2bf(Wu1[k * 64 + mt * 16 + l]);
    } else {
      // wu2b: B-frags of Wu2, [nt 0..3][kk 0..1]
      const int s = r - 20480;
      const int j = s & 7, l = (s >> 3) & 15, q = (s >> 7) & 3;
      const int f = s >> 9, kk = f & 1, nt = f >> 1;
      const int k = kk * 32 + q * 8 + j;
      wu2b[s] = (unsigned short)f2bf(Wu2[k * 64 + nt * 16 + l]);
    }
  }
}

// ------------------------------------------------------------------ pq ----
// PQ^T = Wpq^T x X^T per 16-cell tile; D cols 4-consecutive per lane ->
// packed 8B stores into PQ[cell][128] bf16 row-major.
__global__ __launch_bounds__(256) void pq_kernel(
    const unsigned short* __restrict__ featb,
    const unsigned short* __restrict__ w1pq,
    unsigned short* __restrict__ PQ)
{
  const int lane = threadIdx.x & 63;
  const int wid  = threadIdx.x >> 6;
  const int quad = lane >> 4;
  const int l15  = lane & 15;

  short8 wf[8][2];
  #pragma unroll
  for (int mt = 0; mt < 8; ++mt)
    #pragma unroll
    for (int kk = 0; kk < 2; ++kk)
      wf[mt][kk] = *(const short8*)(w1pq + (((mt * 2 + kk) * 4 + quad) << 7) + l15 * 8);

  const int tile = blockIdx.x * 4 + wid;
  const bool act = (tile < 3125);
  const int  tt  = act ? tile : 3124;
  const int  cr  = tt * 16 + l15;

  short8 xf[2];
  #pragma unroll
  for (int kk = 0; kk < 2; ++kk)
    xf[kk] = *(const short8*)(featb + cr * 64 + kk * 32 + quad * 8);

  f32x4 acc[8] = {};
  #pragma unroll
  for (int kk = 0; kk < 2; ++kk)
    #pragma unroll
    for (int mt = 0; mt < 8; ++mt)
      acc[mt] = __builtin_amdgcn_mfma_f32_16x16x32_bf16(wf[mt][kk], xf[kk], acc[mt], 0, 0, 0);

  if (act) {
    #pragma unroll
    for (int mt = 0; mt < 8; ++mt) {
      uint2 pk;
      pk.x = f2bf(acc[mt][0]) | (f2bf(acc[mt][1]) << 16);
      pk.y = f2bf(acc[mt][2]) | (f2bf(acc[mt][3]) << 16);
      *(uint2*)(PQ + cr * 128 + mt * 16 + quad * 4) = pk;
    }
  }
}

// -------------------------------------------------------------- gather ----
// One wave per cell (4 cells per wave, grid-stride). Quad q handles
// neighbors d = q + 4*dd; lane l15 owns hidden cols [4*l15, 4*l15+4).
// s[i] = (1/16) sum_d silu(P[i] + Q[nbr] + g*w1L + b1), stored bf16.
__global__ __launch_bounds__(256) void gather_kernel(
    const unsigned short* __restrict__ PQ,
    const float4* __restrict__ cent4,
    const int* __restrict__ nbr,
    const float* __restrict__ b1, const float* __restrict__ W1,
    unsigned short* __restrict__ sB)
{
  const int lane = threadIdx.x & 63;
  const int wid  = threadIdx.x >> 6;
  const int quad = lane >> 4;
  const int l15  = lane & 15;
  const int c4   = l15 * 4;

  const f32x4 b1c = *(const f32x4*)(b1 + c4);
  const f32x4 wlc = *(const f32x4*)(W1 + 8192 + c4);   // geom row 128

  for (int c = blockIdx.x * 4 + wid; c < 50000; c += 12500) {
    int nj = 0; float g = 0.f;
    if (lane < 16) {
      nj = nbr[c * DEG + lane];
      const float4 ci = cent4[c];
      const float4 cj = cent4[nj];
      const float dx = ci.x - cj.x, dy = ci.y - cj.y, dz = ci.z - cj.z;
      g = sqrtf(dx * dx + dy * dy + dz * dz);
    }

    const uint2 pv = *(const uint2*)(PQ + c * 128 + c4);   // P cols
    float pc[4];
    pc[0] = bf2f(pv.x & 0xFFFFu) + b1c[0];
    pc[1] = bf2f(pv.x >> 16)     + b1c[1];
    pc[2] = bf2f(pv.y & 0xFFFFu) + b1c[2];
    pc[3] = bf2f(pv.y >> 16)     + b1c[3];

    float acc0 = 0.f, acc1 = 0.f, acc2 = 0.f, acc3 = 0.f;
    #pragma unroll
    for (int dd = 0; dd < 4; ++dd) {
      const int   d  = quad + dd * 4;
      const float gd = __shfl(g, d);
      const int   nd = __shfl(nj, d);
      const uint2 qv = *(const uint2*)(PQ + nd * 128 + 64 + c4);  // Q cols
      acc0 += silu(pc[0] + bf2f(qv.x & 0xFFFFu) + gd * wlc[0]);
      acc1 += silu(pc[1] + bf2f(qv.x >> 16)     + gd * wlc[1]);
      acc2 += silu(pc[2] + bf2f(qv.y & 0xFFFFu) + gd * wlc[2]);
      acc3 += silu(pc[3] + bf2f(qv.y >> 16)     + gd * wlc[3]);
    }
    // sum the 4 quads (each did 4 neighbors)
    acc0 += __shfl_xor(acc0, 16); acc0 += __shfl_xor(acc0, 32);
    acc1 += __shfl_xor(acc1, 16); acc1 += __shfl_xor(acc1, 32);
    acc2 += __shfl_xor(acc2, 16); acc2 += __shfl_xor(acc2, 32);
    acc3 += __shfl_xor(acc3, 16); acc3 += __shfl_xor(acc3, 32);

    if (lane < 16) {
      uint2 pk;
      pk.x = f2bf(acc0 * 0.0625f) | (f2bf(acc1 * 0.0625f) << 16);
      pk.y = f2bf(acc2 * 0.0625f) | (f2bf(acc3 * 0.0625f) << 16);
      *(uint2*)(sB + c * 64 + c4) = pk;
    }
  }
}

// ---------------------------------------------------------------- tail ----
// Per 16-cell tile: msg^T = W2^T x s^T (+b2) -> LDS; hu^T = Wu1^T x [feat|msg]^T
// (+bu1, silu) -> LDS; out = hu x Wu2 + bu2 + feat.
__global__ __launch_bounds__(256) void tail_kernel(
    const unsigned short* __restrict__ featb,
    const unsigned short* __restrict__ sB,
    const float* __restrict__ feat,
    const unsigned short* __restrict__ w2t,
    const unsigned short* __restrict__ wu1t,
    const unsigned short* __restrict__ wu2b,
    const float* __restrict__ b2, const float* __restrict__ bu1,
    const float* __restrict__ bu2,
    float* __restrict__ outf)
{
  __shared__ uint4 smem[4 * 288];   // per wave: Msg 16x144B + Hb 16x144B
  const int lane = threadIdx.x & 63;
  const int wid  = threadIdx.x >> 6;
  const int quad = lane >> 4;
  const int l15  = lane & 15;
  char* Msg = (char*)(smem + wid * 288);
  char* Hb  = Msg + 2304;

  short8 w2f[4][2];
  #pragma unroll
  for (int mt = 0; mt < 4; ++mt)
    #pragma unroll
    for (int kk = 0; kk < 2; ++kk)
      w2f[mt][kk] = *(const short8*)(w2t + (((mt * 2 + kk) * 4 + quad) << 7) + l15 * 8);
  short8 wu1f[4][4];
  #pragma unroll
  for (int mt = 0; mt < 4; ++mt)
    #pragma unroll
    for (int kk = 0; kk < 4; ++kk)
      wu1f[mt][kk] = *(const short8*)(wu1t + (((mt * 4 + kk) * 4 + quad) << 7) + l15 * 8);
  short8 wu2f[4][2];
  #pragma unroll
  for (int nt = 0; nt < 4; ++nt)
    #pragma unroll
    for (int kk = 0; kk < 2; ++kk)
      wu2f[nt][kk] = *(const short8*)(wu2b + (((nt * 2 + kk) * 4 + quad) << 7) + l15 * 8);

  f32x4 b2f[4], bu1f[4];
  #pragma unroll
  for (int mt = 0; mt < 4; ++mt) {
    b2f[mt]  = *(const f32x4*)(b2  + mt * 16 + quad * 4);
    bu1f[mt] = *(const f32x4*)(bu1 + mt * 16 + quad * 4);
  }
  float bu2v[4];
  #pragma unroll
  for (int nt = 0; nt < 4; ++nt) bu2v[nt] = bu2[nt * 16 + l15];

  const int tile = blockIdx.x * 4 + wid;
  const bool act = (tile < 3125);
  const int  tt  = act ? tile : 3124;
  const int  cr  = tt * 16 + l15;

  // stage 1: msg^T = W2^T x s^T (+b2)
  f32x4 accm[4] = {};
  #pragma unroll
  for (int kk = 0; kk < 2; ++kk) {
    const short8 bf = *(const short8*)(sB + cr * 64 + kk * 32 + quad * 8);
    #pragma unroll
    for (int mt = 0; mt < 4; ++mt)
      accm[mt] = __builtin_amdgcn_mfma_f32_16x16x32_bf16(w2f[mt][kk], bf, accm[mt], 0, 0, 0);
  }
  #pragma unroll
  for (int mt = 0; mt < 4; ++mt) {
    uint2 pk;
    pk.x = f2bf(accm[mt][0] + b2f[mt][0]) | (f2bf(accm[mt][1] + b2f[mt][1]) << 16);
    pk.y = f2bf(accm[mt][2] + b2f[mt][2]) | (f2bf(accm[mt][3] + b2f[mt][3]) << 16);
    *(uint2_a*)(Msg + l15 * 144 + mt * 32 + quad * 8) = pk;
  }
  __threadfence_block();

  // stage 2: hu^T = Wu1^T x U^T, U = [feat | msg]
  f32x4 accu[4] = {};
  #pragma unroll
  for (int kk = 0; kk < 4; ++kk) {
    short8 bf;
    if (kk < 2) {
      bf = *(const short8*)(featb + cr * 64 + kk * 32 + quad * 8);
    } else {
      HbRd t; t.u = *(const uint4_a*)(Msg + l15 * 144 + (kk - 2) * 64 + quad * 16);
      bf = t.s;
    }
    #pragma unroll
    for (int mt = 0; mt < 4; ++mt)
      accu[mt] = __builtin_amdgcn_mfma_f32_16x16x32_bf16(wu1f[mt][kk], bf, accu[mt], 0, 0, 0);
  }
  #pragma unroll
  for (int mt = 0; mt < 4; ++mt) {
    float sv[4];
    #pragma unroll
    for (int rg = 0; rg < 4; ++rg)
      sv[rg] = silu(accu[mt][rg] + bu1f[mt][rg]);
    uint2 pk;
    pk.x = f2bf(sv[0]) | (f2bf(sv[1]) << 16);
    pk.y = f2bf(sv[2]) | (f2bf(sv[3]) << 16);
    *(uint2_a*)(Hb + l15 * 144 + mt * 32 + quad * 8) = pk;
  }
  __threadfence_block();

  // stage 3: out = hu x Wu2 + bu2 + feat
  f32x4 acc2[4] = {};
  #pragma unroll
  for (int kk = 0; kk < 2; ++kk) {
    HbRd t; t.u = *(const uint4_a*)(Hb + l15 * 144 + kk * 64 + quad * 16);
    const short8 af = t.s;
    #pragma unroll
    for (int nt = 0; nt < 4; ++nt)
      acc2[nt] = __builtin_amdgcn_mfma_f32_16x16x32_bf16(af, wu2f[nt][kk], acc2[nt], 0, 0, 0);
  }
  if (act) {
    #pragma unroll
    for (int nt = 0; nt < 4; ++nt)
      #pragma unroll
      for (int rg = 0; rg < 4; ++rg) {
        const int row = tt * 16 + quad * 4 + rg;
        const int col = nt * 16 + l15;
        outf[row * 64 + col] = feat[row * 64 + col] + acc2[nt][rg] + bu2v[nt];
      }
  }
}

// -------------------------------------------------------------- launch ----
extern "C" void kernel_launch(void* const* d_in, const int* in_sizes, int n_in,
                              void* d_out, int out_size, void* d_ws, size_t ws_size,
                              hipStream_t stream)
{
  const float* feat = (const float*)d_in[0];
  const float* pos  = (const float*)d_in[1];
  const int*   nbr  = (const int*)d_in[2];
  const float* W1   = (const float*)d_in[3];
  const float* b1   = (const float*)d_in[4];
  const float* W2   = (const float*)d_in[5];
  const float* b2   = (const float*)d_in[6];
  const float* Wu1  = (const float*)d_in[7];
  const float* bu1  = (const float*)d_in[8];
  const float* Wu2  = (const float*)d_in[9];
  const float* bu2  = (const float*)d_in[10];
  float* out = (float*)d_out;

  // ws: featb 6.4MB @0 | PQ bf16 [50000x128] 12.8MB @6.4M | sB 6.4MB @19.2M
  //   | cent4 0.8MB @25.6M | w1pq 16K | w2t 8K | wu1t 16K | wu2b 8K  (~26.5MB)
  unsigned short* featb = (unsigned short*)d_ws;
  unsigned short* PQ    = (unsigned short*)((char*)d_ws + 6400000);
  unsigned short* sB    = (unsigned short*)((char*)d_ws + 19200000);
  float*          cent4 = (float*)((char*)d_ws + 25600000);
  unsigned short* w1pq  = (unsigned short*)((char*)d_ws + 26400000);
  unsigned short* w2t   = (unsigned short*)((char*)d_ws + 26416384);
  unsigned short* wu1t  = (unsigned short*)((char*)d_ws + 26424576);
  unsigned short* wu2b  = (unsigned short*)((char*)d_ws + 26440960);

  prep_kernel<<<4003, 256, 0, stream>>>(feat, pos, W1, W2, Wu1, Wu2,
                                        featb, cent4, out + 3200000,
                                        w1pq, w2t, wu1t, wu2b);
  pq_kernel<<<782, 256, 0, stream>>>(featb, w1pq, PQ);
  gather_kernel<<<3125, 256, 0, stream>>>(PQ, (const float4*)cent4, nbr,
                                          b1, W1, sB);
  tail_kernel<<<782, 256, 0, stream>>>(featb, sB, feat, w2t, wu1t, wu2b,
                                       b2, bu1, bu2, out);
}

// Round 5
// 143.159 us; speedup vs baseline: 1.2470x; 1.0067x over previous
//
#include <hip/hip_runtime.h>

// ETNN layer, N=50000 cells, HID=64, DEG=16 neighbors, 4 nodes/cell, sp=3.
//
// Bilinear split of the per-pair message MLP:
//   x@W1 = f_i@W1[0:64] + f_j@W1[64:128] + geom*W1[128]
// -> aux    : positions passthrough + weight pre-swizzle (MFMA frag order)
// -> prep_pq: feat fp32->bf16 (featb) + centroids + P,Q = feat@[W1top|W1bot]
//             (P: sequentially-read half; Q: randomly-gathered half, in its
//              OWN dense 6.4MB buffer so the gather working set is L2-sized)
// -> gather : s[i] = mean_d silu(P[i] + Q[nbr[i,d]] + g*w1L + b1)
// -> tail   : msg = s@W2+b2; hu = silu([feat|msg]@Wu1+bu1); out = feat+hu@Wu2+bu2
//
// MFMA layouts (HW-verified): A[m=lane&15][k=quad*8+j], B[k=quad*8+j][n=lane&15],
// D[row=quad*4+reg][col=lane&15]. Transposed stages put weights in A so D cols
// land 4-consecutive per lane (packed uint2 stores). Wave-private LDS
// round-trips ordered by __threadfence_block + may_alias types.

#define DEG 16

typedef __attribute__((ext_vector_type(8))) short short8;   // 8 bf16
typedef __attribute__((ext_vector_type(4))) float f32x4;    // MFMA acc
typedef uint2 uint2_a __attribute__((may_alias));
typedef uint4 uint4_a __attribute__((may_alias));

union HbRd { uint4_a u; short8 s; };
union Frag { short8 s; uint4 u; };

__device__ __forceinline__ unsigned f2bf(float f) {
  unsigned u = __float_as_uint(f);
  return (u + 0x7FFFu + ((u >> 16) & 1u)) >> 16;   // RNE fp32->bf16
}
__device__ __forceinline__ float bf2f(unsigned bits16) {
  return __uint_as_float(bits16 << 16);
}
__device__ __forceinline__ float silu(float h) {
  return h / (1.f + __expf(-h));
}

// ----------------------------------------------------------------- aux ----
// t<150000: positions copy (float4) | next 24576: weight pre-swizzle.
__global__ __launch_bounds__(256) void aux_kernel(
    const float* __restrict__ pos,
    const float* __restrict__ W1, const float* __restrict__ W2,
    const float* __restrict__ Wu1, const float* __restrict__ Wu2,
    float* __restrict__ outpos,
    unsigned short* __restrict__ w1pq, unsigned short* __restrict__ w2t,
    unsigned short* __restrict__ wu1t, unsigned short* __restrict__ wu2b)
{
  int t = blockIdx.x * 256 + threadIdx.x;
  if (t < 150000) {
    ((float4*)outpos)[t] = ((const float4*)pos)[t];
  } else if (t < 174576) {
    const int r = t - 150000;
    if (r < 8192) {
      // w1pq: A-frags of [W1top|W1bot]^T, [mt 0..7][kk 0..1]
      const int j = r & 7, l = (r >> 3) & 15, q = (r >> 7) & 3;
      const int f = r >> 9, kk = f & 1, mt = f >> 1;
      const int k = kk * 32 + q * 8 + j;        // feat dim 0..63
      const int m = mt * 16 + l;                // pq col 0..127
      w1pq[r] = (unsigned short)f2bf(
          (m < 64) ? W1[k * 64 + m] : W1[(k + 64) * 64 + (m - 64)]);
    } else if (r < 12288) {
      // w2t: A-frags of W2^T, [mt 0..3][kk 0..1]
      const int s = r - 8192;
      const int j = s & 7, l = (s >> 3) & 15, q = (s >> 7) & 3;
      const int f = s >> 9, kk = f & 1, mt = f >> 1;
      const int k = kk * 32 + q * 8 + j;
      w2t[s] = (unsigned short)f2bf(W2[k * 64 + mt * 16 + l]);
    } else if (r < 20480) {
      // wu1t: A-frags of Wu1^T, [mt 0..3][kk 0..3]
      const int s = r - 12288;
      const int j = s & 7, l = (s >> 3) & 15, q = (s >> 7) & 3;
      const int f = s >> 9, kk = f & 3, mt = f >> 2;
      const int k = kk * 32 + q * 8 + j;        // 0..127
      wu1t[s] = (unsigned short)f2bf(Wu1[k * 64 + mt * 16 + l]);
    } else {
      // wu2b: B-frags of Wu2, [nt 0..3][kk 0..1]
      const int s = r - 20480;
      const int j = s & 7, l = (s >> 3) & 15, q = (s >> 7) & 3;
      const int f = s >> 9, kk = f & 1, nt = f >> 1;
      const int k = kk * 32 + q * 8 + j;
      wu2b[s] = (unsigned short)f2bf(Wu2[k * 64 + nt * 16 + l]);
    }
  }
}

// ------------------------------------------------------------- prep_pq ----
// One wave per 16-cell tile: read feat fp32 (B-frag layout), convert to bf16
// (write featb + keep frags), centroids for own cells, then
// [P|Q]^T = Wpq^T x X^T ; packed uint2 stores into split P / Q buffers.
__global__ __launch_bounds__(256) void prep_pq_kernel(
    const float* __restrict__ feat, const float* __restrict__ pos,
    const unsigned short* __restrict__ w1pq,
    unsigned short* __restrict__ featb, float* __restrict__ cent4,
    unsigned short* __restrict__ Pb, unsigned short* __restrict__ Qb)
{
  const int lane = threadIdx.x & 63;
  const int wid  = threadIdx.x >> 6;
  const int quad = lane >> 4;
  const int l15  = lane & 15;

  const int tile = blockIdx.x * 4 + wid;
  const bool act = (tile < 3125);
  const int  tt  = act ? tile : 3124;
  const int  cr  = tt * 16 + l15;

  // feat rows -> bf16 frags (B-layout) + featb store
  short8 xf[2];
  #pragma unroll
  for (int kk = 0; kk < 2; ++kk) {
    const float4 f0 = *(const float4*)(feat + cr * 64 + kk * 32 + quad * 8);
    const float4 f1 = *(const float4*)(feat + cr * 64 + kk * 32 + quad * 8 + 4);
    Frag v;
    v.s[0] = (short)f2bf(f0.x); v.s[1] = (short)f2bf(f0.y);
    v.s[2] = (short)f2bf(f0.z); v.s[3] = (short)f2bf(f0.w);
    v.s[4] = (short)f2bf(f1.x); v.s[5] = (short)f2bf(f1.y);
    v.s[6] = (short)f2bf(f1.z); v.s[7] = (short)f2bf(f1.w);
    xf[kk] = v.s;
    if (act) *(uint4*)(featb + cr * 64 + kk * 32 + quad * 8) = v.u;
  }

  // centroid of own 4 nodes (lanes 0..15, one cell each)
  if (act && lane < 16) {
    const float4* pp = (const float4*)(pos + 12 * cr);
    const float4 a = pp[0], b = pp[1], c = pp[2];
    float4 o;
    o.x = (a.x + a.w + b.z + c.y) * 0.25f;
    o.y = (a.y + b.x + b.w + c.z) * 0.25f;
    o.z = (a.z + b.y + c.x + c.w) * 0.25f;
    o.w = 0.f;
    ((float4*)cent4)[cr] = o;
  }

  short8 wf[8][2];
  #pragma unroll
  for (int mt = 0; mt < 8; ++mt)
    #pragma unroll
    for (int kk = 0; kk < 2; ++kk)
      wf[mt][kk] = *(const short8*)(w1pq + (((mt * 2 + kk) * 4 + quad) << 7) + l15 * 8);

  f32x4 acc[8] = {};
  #pragma unroll
  for (int kk = 0; kk < 2; ++kk)
    #pragma unroll
    for (int mt = 0; mt < 8; ++mt)
      acc[mt] = __builtin_amdgcn_mfma_f32_16x16x32_bf16(wf[mt][kk], xf[kk], acc[mt], 0, 0, 0);

  if (act) {
    #pragma unroll
    for (int mt = 0; mt < 8; ++mt) {
      uint2 pk;
      pk.x = f2bf(acc[mt][0]) | (f2bf(acc[mt][1]) << 16);
      pk.y = f2bf(acc[mt][2]) | (f2bf(acc[mt][3]) << 16);
      unsigned short* dst = (mt < 4)
          ? Pb + cr * 64 + mt * 16 + quad * 4
          : Qb + cr * 64 + (mt - 4) * 16 + quad * 4;
      *(uint2*)dst = pk;
    }
  }
}

// -------------------------------------------------------------- gather ----
// One wave per cell (4 per wave, grid-stride). Quad q handles neighbors
// d = q + 4*dd; lane l15 owns hidden cols [4*l15, 4*l15+4).
// s[i] = (1/16) sum_d silu(P[i] + Q[nbr] + g*w1L + b1), stored bf16.
// Q is a dense 6.4MB buffer -> random-gather working set is L2-sized.
__global__ __launch_bounds__(256) void gather_kernel(
    const unsigned short* __restrict__ Pb,
    const unsigned short* __restrict__ Qb,
    const float4* __restrict__ cent4,
    const int* __restrict__ nbr,
    const float* __restrict__ b1, const float* __restrict__ W1,
    unsigned short* __restrict__ sB)
{
  const int lane = threadIdx.x & 63;
  const int wid  = threadIdx.x >> 6;
  const int quad = lane >> 4;
  const int l15  = lane & 15;
  const int c4   = l15 * 4;

  const f32x4 b1c = *(const f32x4*)(b1 + c4);
  const f32x4 wlc = *(const f32x4*)(W1 + 8192 + c4);   // geom row 128

  for (int c = blockIdx.x * 4 + wid; c < 50000; c += 12500) {
    int nj = 0; float g = 0.f;
    if (lane < 16) {
      nj = nbr[c * DEG + lane];
      const float4 ci = cent4[c];
      const float4 cj = cent4[nj];
      const float dx = ci.x - cj.x, dy = ci.y - cj.y, dz = ci.z - cj.z;
      g = sqrtf(dx * dx + dy * dy + dz * dz);
    }

    const uint2 pv = *(const uint2*)(Pb + c * 64 + c4);
    float pc[4];
    pc[0] = bf2f(pv.x & 0xFFFFu) + b1c[0];
    pc[1] = bf2f(pv.x >> 16)     + b1c[1];
    pc[2] = bf2f(pv.y & 0xFFFFu) + b1c[2];
    pc[3] = bf2f(pv.y >> 16)     + b1c[3];

    float acc0 = 0.f, acc1 = 0.f, acc2 = 0.f, acc3 = 0.f;
    #pragma unroll
    for (int dd = 0; dd < 4; ++dd) {
      const int   d  = quad + dd * 4;
      const float gd = __shfl(g, d);
      const int   nd = __shfl(nj, d);
      const uint2 qv = *(const uint2*)(Qb + nd * 64 + c4);
      acc0 += silu(pc[0] + bf2f(qv.x & 0xFFFFu) + gd * wlc[0]);
      acc1 += silu(pc[1] + bf2f(qv.x >> 16)     + gd * wlc[1]);
      acc2 += silu(pc[2] + bf2f(qv.y & 0xFFFFu) + gd * wlc[2]);
      acc3 += silu(pc[3] + bf2f(qv.y >> 16)     + gd * wlc[3]);
    }
    acc0 += __shfl_xor(acc0, 16); acc0 += __shfl_xor(acc0, 32);
    acc1 += __shfl_xor(acc1, 16); acc1 += __shfl_xor(acc1, 32);
    acc2 += __shfl_xor(acc2, 16); acc2 += __shfl_xor(acc2, 32);
    acc3 += __shfl_xor(acc3, 16); acc3 += __shfl_xor(acc3, 32);

    if (lane < 16) {
      uint2 pk;
      pk.x = f2bf(acc0 * 0.0625f) | (f2bf(acc1 * 0.0625f) << 16);
      pk.y = f2bf(acc2 * 0.0625f) | (f2bf(acc3 * 0.0625f) << 16);
      *(uint2*)(sB + c * 64 + c4) = pk;
    }
  }
}

// ---------------------------------------------------------------- tail ----
// Per 16-cell tile: msg^T = W2^T x s^T (+b2) -> LDS; hu^T = Wu1^T x [feat|msg]^T
// (+bu1, silu) -> LDS; out = hu x Wu2 + bu2 + feat.
__global__ __launch_bounds__(256) void tail_kernel(
    const unsigned short* __restrict__ featb,
    const unsigned short* __restrict__ sB,
    const float* __restrict__ feat,
    const unsigned short* __restrict__ w2t,
    const unsigned short* __restrict__ wu1t,
    const unsigned short* __restrict__ wu2b,
    const float* __restrict__ b2, const float* __restrict__ bu1,
    const float* __restrict__ bu2,
    float* __restrict__ outf)
{
  __shared__ uint4 smem[4 * 288];   // per wave: Msg 16x144B + Hb 16x144B
  const int lane = threadIdx.x & 63;
  const int wid  = threadIdx.x >> 6;
  const int quad = lane >> 4;
  const int l15  = lane & 15;
  char* Msg = (char*)(smem + wid * 288);
  char* Hb  = Msg + 2304;

  short8 w2f[4][2];
  #pragma unroll
  for (int mt = 0; mt < 4; ++mt)
    #pragma unroll
    for (int kk = 0; kk < 2; ++kk)
      w2f[mt][kk] = *(const short8*)(w2t + (((mt * 2 + kk) * 4 + quad) << 7) + l15 * 8);
  short8 wu1f[4][4];
  #pragma unroll
  for (int mt = 0; mt < 4; ++mt)
    #pragma unroll
    for (int kk = 0; kk < 4; ++kk)
      wu1f[mt][kk] = *(const short8*)(wu1t + (((mt * 4 + kk) * 4 + quad) << 7) + l15 * 8);
  short8 wu2f[4][2];
  #pragma unroll
  for (int nt = 0; nt < 4; ++nt)
    #pragma unroll
    for (int kk = 0; kk < 2; ++kk)
      wu2f[nt][kk] = *(const short8*)(wu2b + (((nt * 2 + kk) * 4 + quad) << 7) + l15 * 8);

  f32x4 b2f[4], bu1f[4];
  #pragma unroll
  for (int mt = 0; mt < 4; ++mt) {
    b2f[mt]  = *(const f32x4*)(b2  + mt * 16 + quad * 4);
    bu1f[mt] = *(const f32x4*)(bu1 + mt * 16 + quad * 4);
  }
  float bu2v[4];
  #pragma unroll
  for (int nt = 0; nt < 4; ++nt) bu2v[nt] = bu2[nt * 16 + l15];

  const int tile = blockIdx.x * 4 + wid;
  const bool act = (tile < 3125);
  const int  tt  = act ? tile : 3124;
  const int  cr  = tt * 16 + l15;

  // stage 1: msg^T = W2^T x s^T (+b2)
  f32x4 accm[4] = {};
  #pragma unroll
  for (int kk = 0; kk < 2; ++kk) {
    const short8 bf = *(const short8*)(sB + cr * 64 + kk * 32 + quad * 8);
    #pragma unroll
    for (int mt = 0; mt < 4; ++mt)
      accm[mt] = __builtin_amdgcn_mfma_f32_16x16x32_bf16(w2f[mt][kk], bf, accm[mt], 0, 0, 0);
  }
  #pragma unroll
  for (int mt = 0; mt < 4; ++mt) {
    uint2 pk;
    pk.x = f2bf(accm[mt][0] + b2f[mt][0]) | (f2bf(accm[mt][1] + b2f[mt][1]) << 16);
    pk.y = f2bf(accm[mt][2] + b2f[mt][2]) | (f2bf(accm[mt][3] + b2f[mt][3]) << 16);
    *(uint2_a*)(Msg + l15 * 144 + mt * 32 + quad * 8) = pk;
  }
  __threadfence_block();

  // stage 2: hu^T = Wu1^T x U^T, U = [feat | msg]
  f32x4 accu[4] = {};
  #pragma unroll
  for (int kk = 0; kk < 4; ++kk) {
    short8 bf;
    if (kk < 2) {
      bf = *(const short8*)(featb + cr * 64 + kk * 32 + quad * 8);
    } else {
      HbRd t; t.u = *(const uint4_a*)(Msg + l15 * 144 + (kk - 2) * 64 + quad * 16);
      bf = t.s;
    }
    #pragma unroll
    for (int mt = 0; mt < 4; ++mt)
      accu[mt] = __builtin_amdgcn_mfma_f32_16x16x32_bf16(wu1f[mt][kk], bf, accu[mt], 0, 0, 0);
  }
  #pragma unroll
  for (int mt = 0; mt < 4; ++mt) {
    float sv[4];
    #pragma unroll
    for (int rg = 0; rg < 4; ++rg)
      sv[rg] = silu(accu[mt][rg] + bu1f[mt][rg]);
    uint2 pk;
    pk.x = f2bf(sv[0]) | (f2bf(sv[1]) << 16);
    pk.y = f2bf(sv[2]) | (f2bf(sv[3]) << 16);
    *(uint2_a*)(Hb + l15 * 144 + mt * 32 + quad * 8) = pk;
  }
  __threadfence_block();

  // stage 3: out = hu x Wu2 + bu2 + feat
  f32x4 acc2[4] = {};
  #pragma unroll
  for (int kk = 0; kk < 2; ++kk) {
    HbRd t; t.u = *(const uint4_a*)(Hb + l15 * 144 + kk * 64 + quad * 16);
    const short8 af = t.s;
    #pragma unroll
    for (int nt = 0; nt < 4; ++nt)
      acc2[nt] = __builtin_amdgcn_mfma_f32_16x16x32_bf16(af, wu2f[nt][kk], acc2[nt], 0, 0, 0);
  }
  if (act) {
    #pragma unroll
    for (int nt = 0; nt < 4; ++nt)
      #pragma unroll
      for (int rg = 0; rg < 4; ++rg) {
        const int row = tt * 16 + quad * 4 + rg;
        const int col = nt * 16 + l15;
        outf[row * 64 + col] = feat[row * 64 + col] + acc2[nt][rg] + bu2v[nt];
      }
  }
}

// -------------------------------------------------------------- launch ----
extern "C" void kernel_launch(void* const* d_in, const int* in_sizes, int n_in,
                              void* d_out, int out_size, void* d_ws, size_t ws_size,
                              hipStream_t stream)
{
  const float* feat = (const float*)d_in[0];
  const float* pos  = (const float*)d_in[1];
  const int*   nbr  = (const int*)d_in[2];
  const float* W1   = (const float*)d_in[3];
  const float* b1   = (const float*)d_in[4];
  const float* W2   = (const float*)d_in[5];
  const float* b2   = (const float*)d_in[6];
  const float* Wu1  = (const float*)d_in[7];
  const float* bu1  = (const float*)d_in[8];
  const float* Wu2  = (const float*)d_in[9];
  const float* bu2  = (const float*)d_in[10];
  float* out = (float*)d_out;

  // ws: featb 6.4M @0 | Pb 6.4M @6.4M | Qb 6.4M @12.8M (dense random-gather
  // set) | sB 6.4M @19.2M | cent4 0.8M @25.6M | swizzled weights @26.4M
  unsigned short* featb = (unsigned short*)d_ws;
  unsigned short* Pb    = (unsigned short*)((char*)d_ws + 6400000);
  unsigned short* Qb    = (unsigned short*)((char*)d_ws + 12800000);
  unsigned short* sB    = (unsigned short*)((char*)d_ws + 19200000);
  float*          cent4 = (float*)((char*)d_ws + 25600000);
  unsigned short* w1pq  = (unsigned short*)((char*)d_ws + 26400000);
  unsigned short* w2t   = (unsigned short*)((char*)d_ws + 26416384);
  unsigned short* wu1t  = (unsigned short*)((char*)d_ws + 26424576);
  unsigned short* wu2b  = (unsigned short*)((char*)d_ws + 26440960);

  aux_kernel<<<682, 256, 0, stream>>>(pos, W1, W2, Wu1, Wu2, out + 3200000,
                                      w1pq, w2t, wu1t, wu2b);
  prep_pq_kernel<<<782, 256, 0, stream>>>(feat, pos, w1pq, featb, cent4, Pb, Qb);
  gather_kernel<<<3125, 256, 0, stream>>>(Pb, Qb, (const float4*)cent4, nbr,
                                          b1, W1, sB);
  tail_kernel<<<782, 256, 0, stream>>>(featb, sB, feat, w2t, wu1t, wu2b,
                                       b2, bu1, bu2, out);
}